// Round 2
// baseline (161.970 us; speedup 1.0000x reference)
//
#include <hip/hip_runtime.h>
#include <hip/hip_bf16.h>

// B=8, S=128, E=50, D=300, DE=50 — ALL I/O FLOAT32.
// out: node[307200] | edge[6553600].
// ws (floats): R1[51200] | R2[51200]
//
// R1 change: k_node restructured 256x1024 (1 block/CU) -> 512x512 (2 blocks/CU),
// 2 rows/block. Same split-K chain lengths, half the LDS, two independent
// blocks per CU overlap barrier drains + narrow reduce phases.

typedef __bf16 bf16x8 __attribute__((ext_vector_type(8)));
typedef float f32x4 __attribute__((ext_vector_type(4)));
typedef float f32x2 __attribute__((ext_vector_type(2)));

__device__ __forceinline__ unsigned short f2bf(float f) {
    __hip_bfloat16 h = __float2bfloat16(f);
    union { __hip_bfloat16 h; unsigned short u; } c; c.h = h; return c.u;
}

// ---------------- K1: 2 rows/block, 512 thr, split-K x4 (128-wide d tiling) ----
// phase 0: M rows from wps (fused msum) + diag(wa)
// Axm=M@x ; h=Axm@Ww+Wb ; LN(unbiased+eps) ; relu ; R1/R2.
__global__ void __launch_bounds__(512) k_node(
    const float* __restrict__ wps,
    const float* __restrict__ wa,
    const float* __restrict__ x,
    const float* __restrict__ Ww,
    const float* __restrict__ Wb,
    const float* __restrict__ lna,
    const float* __restrict__ lnb,
    const float* __restrict__ Rw,
    const float* __restrict__ rb,
    float* __restrict__ node_out,
    float* __restrict__ R1, float* __restrict__ R2)
{
    __shared__ __align__(16) float axp[2432];   // partials: msum/axm/h, then q1|q2
    __shared__ __align__(16) float axm2[608];   // axm[304][2]
    __shared__ __align__(16) float Mlt[256];    // M[j][2 rows]
    __shared__ __align__(16) float srcL[704];   // [diag(50)|node(300)+pad][2]
    __shared__ float red1[10], red2[10], stats[4];

    int tid = threadIdx.x;
    int row0 = blockIdx.x * 2;
    int b = row0 >> 7, i0 = row0 & 127;

    // ---- phase 0a: fused msum — 512 threads, half a (r,j) row each ----
    {
        int p = tid & 255, h = tid >> 8;        // pair, half
        int r = p >> 7, j = p & 127;
        const float2* pp = (const float2*)(wps + ((size_t)(row0 + r) * 128 + j) * 50);
        float s = 0.f;
        if (h == 0) {
#pragma unroll
            for (int n = 0; n < 13; ++n) { float2 v = pp[n]; s += v.x + v.y; }
        } else {
#pragma unroll
            for (int n = 13; n < 25; ++n) { float2 v = pp[n]; s += v.x + v.y; }
        }
        axp[tid] = s;
    }
    __syncthreads();
    // ---- phase 0b: combine halves -> Mlt, and load diag(wa) ----
    if (tid < 256) {
        int r = tid >> 7, j = tid & 127;
        float s = axp[tid] + axp[tid + 256];
        Mlt[j * 2 + r] = s * (1.0f / 50.0f) + (((i0 + r) == j) ? 1.0f : 0.0f);
    } else if (tid < 356) {
        int idx = tid - 256, r = idx / 50, e = idx % 50;
        srcL[e * 2 + r] = wa[((size_t)(row0 + r) * 128 + (i0 + r)) * 50 + e];
    }
    __syncthreads();

    int t = tid & 127, g = tid >> 7;           // d-lane, K-group (0..3)
    bool has3 = (t < 44);
    int d2 = has3 ? 256 + t : 299;

    // ---- phase 1: Axm partials, group g covers j in [32g, 32g+32) ----
    {
        f32x2 a0 = {0.f, 0.f}, a1 = {0.f, 0.f}, a2 = {0.f, 0.f};
        const float* xp = x + (size_t)b * 38400;
        int j0 = g * 32;
#pragma unroll 8
        for (int jj = 0; jj < 32; ++jj) {
            int j = j0 + jj;
            f32x2 m2 = *(const f32x2*)&Mlt[j * 2];
            float xv0 = xp[j * 300 + t];
            float xv1 = xp[j * 300 + 128 + t];
            float xv2 = xp[j * 300 + d2];
            a0 += m2 * xv0;
            a1 += m2 * xv1;
            a2 += m2 * xv2;
        }
        *(f32x2*)&axp[t * 8 + g * 2] = a0;
        *(f32x2*)&axp[(128 + t) * 8 + g * 2] = a1;
        if (has3) *(f32x2*)&axp[(256 + t) * 8 + g * 2] = a2;
    }
    __syncthreads();
    if (tid < 300) {                       // reduce -> axm[k][2]
        f32x2 s = *(f32x2*)&axp[tid * 8]     + *(f32x2*)&axp[tid * 8 + 2]
                + *(f32x2*)&axp[tid * 8 + 4] + *(f32x2*)&axp[tid * 8 + 6];
        *(f32x2*)&axm2[tid * 2] = s;
    }
    __syncthreads();

    // ---- phase 2: h partials, group g covers k in [75g, 75g+75) ----
    {
        f32x2 h0 = {0.f, 0.f}, h1 = {0.f, 0.f}, h2 = {0.f, 0.f};
        int kb = g * 75, ke = kb + 75;
#pragma unroll 4
        for (int k = kb; k < ke; ++k) {
            f32x2 m2 = *(const f32x2*)&axm2[k * 2];
            float w0 = Ww[k * 300 + t];
            float w1 = Ww[k * 300 + 128 + t];
            float w2 = Ww[k * 300 + d2];
            h0 += m2 * w0;
            h1 += m2 * w1;
            h2 += m2 * w2;
        }
        *(f32x2*)&axp[t * 8 + g * 2] = h0;
        *(f32x2*)&axp[(128 + t) * 8 + g * 2] = h1;
        if (has3) *(f32x2*)&axp[(256 + t) * 8 + g * 2] = h2;
    }
    __syncthreads();

    // ---- h reduce + LN stats ----
    f32x2 hv = {0.f, 0.f};
    int wv = tid >> 6, lane = tid & 63;
    if (tid < 320) {
        if (tid < 300) {
            hv = *(f32x2*)&axp[tid * 8]     + *(f32x2*)&axp[tid * 8 + 2]
               + *(f32x2*)&axp[tid * 8 + 4] + *(f32x2*)&axp[tid * 8 + 6];
            hv += Wb[tid];
        }
        float s1r[2], s2r[2];
#pragma unroll
        for (int r = 0; r < 2; ++r) { s1r[r] = hv[r]; s2r[r] = hv[r] * hv[r]; }
        for (int off = 32; off; off >>= 1) {
#pragma unroll
            for (int r = 0; r < 2; ++r) {
                s1r[r] += __shfl_down(s1r[r], off);
                s2r[r] += __shfl_down(s2r[r], off);
            }
        }
        if (lane == 0) {
#pragma unroll
            for (int r = 0; r < 2; ++r) { red1[wv * 2 + r] = s1r[r]; red2[wv * 2 + r] = s2r[r]; }
        }
    }
    __syncthreads();
    if (tid < 2) {
        float s1 = 0.f, s2 = 0.f;
#pragma unroll
        for (int w = 0; w < 5; ++w) { s1 += red1[w * 2 + tid]; s2 += red2[w * 2 + tid]; }
        float mean = s1 * (1.0f / 300.0f);
        float var = (s2 - 300.0f * mean * mean) * (1.0f / 299.0f);
        var = fmaxf(var, 0.0f);
        stats[tid * 2] = mean;
        stats[tid * 2 + 1] = 1.0f / (sqrtf(var) + 1e-6f);
    }
    __syncthreads();

    // ---- apply LN + relu -> node_out + srcL ----
    if (tid < 300) {
        float la = lna[tid], lb = lnb[tid];
        f32x2 nv;
#pragma unroll
        for (int r = 0; r < 2; ++r) {
            float v = la * (hv[r] - stats[r * 2]) * stats[r * 2 + 1] + lb;
            v = fmaxf(v, 0.f);
            nv[r] = v;
            node_out[(size_t)(row0 + r) * 300 + tid] = v;
        }
        *(f32x2*)&srcL[(50 + tid) * 2] = nv;
    }
    __syncthreads();

    // ---- phase 3: R1/R2 partials, 10 chunks of 35 over concat K=350 ----
    if (tid < 500) {
        int p = tid / 50, k = tid % 50;
        f32x2 r1a = {0.f, 0.f}, r2a = {0.f, 0.f};
        int ib = p * 35;
#pragma unroll 5
        for (int idx = ib; idx < ib + 35; ++idx) {
            f32x2 sv = *(const f32x2*)&srcL[idx * 2];
            float w1, w2;
            if (idx < 50) { w1 = Rw[(50 + idx) * 50 + k]; w2 = Rw[(100 + idx) * 50 + k]; }
            else { int d = idx - 50; w1 = Rw[(150 + d) * 50 + k]; w2 = Rw[(450 + d) * 50 + k]; }
            r1a += sv * w1;
            r2a += sv * w2;
        }
        *(f32x2*)&axp[(p * 50 + k) * 2] = r1a;
        *(f32x2*)&axp[1024 + (p * 50 + k) * 2] = r2a;
    }
    __syncthreads();
    if (tid < 100) {
        int r = tid / 50, k = tid % 50;
        float s1 = 0.f, s2 = rb[k];
#pragma unroll
        for (int p = 0; p < 10; ++p) {
            s1 += axp[(p * 50 + k) * 2 + r];
            s2 += axp[1024 + (p * 50 + k) * 2 + r];
        }
        R1[(size_t)(row0 + r) * 50 + k] = s1;
        R2[(size_t)(row0 + r) * 50 + k] = s2;
    }
}

// ---------------- K2: edge_out = wa·Rw[0:50] (MFMA) + R1[j] + R2[i] ------------
__global__ void __launch_bounds__(256) k_edge(
    const float* __restrict__ wa,
    const float* __restrict__ Rw,
    const float* __restrict__ R1, const float* __restrict__ R2,
    float* __restrict__ eout)
{
    __shared__ __align__(16) unsigned char smem[27648];
    unsigned short* waA  = (unsigned short*)smem;            // 128*72 bf16
    unsigned short* rwBT = (unsigned short*)(smem + 18432);  // 64*72 bf16
    float* outF = (float*)smem;                              // alias: 6400 floats
    int tid = threadIdx.x;
    int bi = blockIdx.x;       // b*128 + i
    int b = bi >> 7;

    for (int idx = tid; idx < 2304; idx += 256) ((unsigned int*)rwBT)[idx] = 0u;
    for (int idx = tid; idx < 1408; idx += 256) {            // zero waA pad e in [50,72)
        int j = idx / 11, c = idx % 11;
        *((unsigned int*)(waA + j * 72 + 50) + c) = 0u;
    }
    __syncthreads();

    const float2* wap = (const float2*)(wa + (size_t)bi * 6400);
    for (int idx = tid; idx < 3200; idx += 256) {
        float2 v = wap[idx];
        int f = idx * 2;
        int j = f / 50, e = f % 50;
        unsigned int pack = (unsigned int)f2bf(v.x) | ((unsigned int)f2bf(v.y) << 16);
        *(unsigned int*)(waA + j * 72 + e) = pack;
    }
    for (int idx = tid; idx < 2500; idx += 256) {            // transpose+cvt Rw[0:50][0:50]
        int e = idx / 50, kk = idx % 50;
        rwBT[kk * 72 + e] = f2bf(Rw[idx]);
    }
    __syncthreads();

    int lane = tid & 63, wv = tid >> 6;
    int q = lane >> 4, lr = lane & 15;
    f32x4 acc[2][4] = {};

#pragma unroll
    for (int ks = 0; ks < 2; ++ks) {
        int e0 = ks * 32 + q * 8;
        bf16x8 a0 = *(const bf16x8*)&waA[(wv * 32 + lr) * 72 + e0];
        bf16x8 a1 = *(const bf16x8*)&waA[(wv * 32 + 16 + lr) * 72 + e0];
#pragma unroll
        for (int nt = 0; nt < 4; ++nt) {
            bf16x8 bb = *(const bf16x8*)&rwBT[(nt * 16 + lr) * 72 + e0];
            acc[0][nt] = __builtin_amdgcn_mfma_f32_16x16x32_bf16(a0, bb, acc[0][nt], 0, 0, 0);
            acc[1][nt] = __builtin_amdgcn_mfma_f32_16x16x32_bf16(a1, bb, acc[1][nt], 0, 0, 0);
        }
    }
    __syncthreads();   // staging LDS dead; alias as outF

    const float* r2p = R2 + (size_t)bi * 50;
#pragma unroll
    for (int nt = 0; nt < 4; ++nt) {
        int kk = nt * 16 + lr;
        if (kk < 50) {
            float r2v = r2p[kk];
#pragma unroll
            for (int mi = 0; mi < 2; ++mi) {
                int jbase = wv * 32 + mi * 16 + q * 4;
#pragma unroll
                for (int r = 0; r < 4; ++r)
                    outF[(jbase + r) * 50 + kk] = acc[mi][nt][r] + r2v;
            }
        }
    }
    __syncthreads();

    const float4* R1b = (const float4*)(R1 + (size_t)b * 6400);
    const float4* L4  = (const float4*)outF;
    float4* op4 = (float4*)(eout + (size_t)bi * 6400);
    for (int f4 = tid; f4 < 1600; f4 += 256) {
        float4 v = L4[f4];
        float4 r = R1b[f4];
        v.x += r.x; v.y += r.y; v.z += r.z; v.w += r.w;
        op4[f4] = v;
    }
}

extern "C" void kernel_launch(void* const* d_in, const int* in_sizes, int n_in,
                              void* d_out, int out_size, void* d_ws, size_t ws_size,
                              hipStream_t stream)
{
    const float* wps = (const float*)d_in[0];
    const float* wa  = (const float*)d_in[1];
    const float* x   = (const float*)d_in[2];
    // d_in[3] self_loop: identity on every channel, folded into fused msum (+1 on diag)
    const float* Ww  = (const float*)d_in[4];
    const float* Wb  = (const float*)d_in[5];
    const float* lna = (const float*)d_in[6];
    const float* lnb = (const float*)d_in[7];
    const float* Rw  = (const float*)d_in[8];
    const float* rb  = (const float*)d_in[9];

    float* R1 = (float*)d_ws;                    // 51200 floats
    float* R2 = ((float*)d_ws) + 51200;          // 51200 floats

    float* node_out = (float*)d_out;             // 307200 floats
    float* edge_out = node_out + 307200;         // 6553600 floats

    k_node<<<512, 512, 0, stream>>>(wps, wa, x, Ww, Wb, lna, lnb, Rw, rb,
                                    node_out, R1, R2);
    k_edge<<<1024, 256, 0, stream>>>(wa, Rw, R1, R2, edge_out);
}

// Round 3
// 149.668 us; speedup vs baseline: 1.0822x; 1.0822x over previous
//
#include <hip/hip_runtime.h>
#include <hip/hip_bf16.h>

// B=8, S=128, E=50, D=300, DE=50 — ALL I/O FLOAT32.
// out: node[307200] | edge[6553600].
// ws (floats): R1[51200] | R2[51200]
//
// R2 change: k_node -> 512 blocks x 1024 threads, 2 rows/block:
//  - 2 blocks/CU x 16 waves = 32 waves/CU (was 16) to hide latency/barriers
//  - partials layout [g][d][2] (lane-contiguous, kills 8-way bank conflicts)
//  - phase 0a: quad-per-row coalesced wps loads + shfl reduce (no LDS staging,
//    one barrier fewer)

typedef __bf16 bf16x8 __attribute__((ext_vector_type(8)));
typedef float f32x4 __attribute__((ext_vector_type(4)));
typedef float f32x2 __attribute__((ext_vector_type(2)));

__device__ __forceinline__ unsigned short f2bf(float f) {
    __hip_bfloat16 h = __float2bfloat16(f);
    union { __hip_bfloat16 h; unsigned short u; } c; c.h = h; return c.u;
}

// ---------------- K1: 2 rows/block, 1024 thr, split-K x4 ----------------------
__global__ void __launch_bounds__(1024, 8) k_node(
    const float* __restrict__ wps,
    const float* __restrict__ wa,
    const float* __restrict__ x,
    const float* __restrict__ Ww,
    const float* __restrict__ Wb,
    const float* __restrict__ lna,
    const float* __restrict__ lnb,
    const float* __restrict__ Rw,
    const float* __restrict__ rb,
    float* __restrict__ node_out,
    float* __restrict__ R1, float* __restrict__ R2)
{
    __shared__ __align__(16) float axp[5600];   // [g][d][2] partials; phase3: q1|q2
    __shared__ __align__(16) float axm2[608];   // axm[304][2]
    __shared__ __align__(16) float Mlt[256];    // M[j][2 rows]
    __shared__ __align__(16) float srcL[704];   // [diag(50)|node(300)+pad][2]
    __shared__ float red1[10], red2[10], stats[4];

    int tid = threadIdx.x;
    int row0 = blockIdx.x * 2;
    int b = row0 >> 7, i0 = row0 & 127;

    // ---- phase 0: fused msum, quad-coalesced; + diag(wa) ----
    {
        int pair = tid >> 2, q = tid & 3;           // 256 pairs x 4 lanes
        int r = pair >> 7, j = pair & 127;
        const float2* p2 = (const float2*)(wps + ((size_t)(row0 + r) * 128 + j) * 50);
        float s = 0.f;
#pragma unroll
        for (int k = 0; k < 6; ++k) { float2 v = p2[q + k * 4]; s += v.x + v.y; }
        if (q == 0) { float2 v = p2[24]; s += v.x + v.y; }
        s += __shfl_xor(s, 1);
        s += __shfl_xor(s, 2);
        if (q == 0)
            Mlt[j * 2 + r] = s * (1.0f / 50.0f) + (((i0 + r) == j) ? 1.0f : 0.0f);
    }
    if (tid < 100) {
        int r = tid / 50, e = tid % 50;
        srcL[e * 2 + r] = wa[((size_t)(row0 + r) * 128 + (i0 + r)) * 50 + e];
    }
    __syncthreads();

    int t = tid & 255, g = tid >> 8;               // d-lane, K-group (0..3)
    bool has2 = (t < 44);
    int d1 = has2 ? 256 + t : 299;

    // ---- phase 1: Axm partials, group g covers j in [32g, 32g+32) ----
    {
        f32x2 a0 = {0.f, 0.f}, a1 = {0.f, 0.f};
        const float* xp = x + (size_t)b * 38400;
        int j0 = g * 32;
#pragma unroll 8
        for (int jj = 0; jj < 32; ++jj) {
            int j = j0 + jj;
            f32x2 m2 = *(const f32x2*)&Mlt[j * 2];
            a0 += m2 * xp[j * 300 + t];
            a1 += m2 * xp[j * 300 + d1];
        }
        *(f32x2*)&axp[g * 608 + t * 2] = a0;
        if (has2) *(f32x2*)&axp[g * 608 + d1 * 2] = a1;
    }
    __syncthreads();
    if (tid < 300) {                       // reduce -> axm[k][2]
        f32x2 s = *(f32x2*)&axp[tid * 2]        + *(f32x2*)&axp[608 + tid * 2]
                + *(f32x2*)&axp[1216 + tid * 2] + *(f32x2*)&axp[1824 + tid * 2];
        *(f32x2*)&axm2[tid * 2] = s;
    }
    __syncthreads();

    // ---- phase 2: h partials, group g covers k in [75g, 75g+75) ----
    {
        f32x2 h0 = {0.f, 0.f}, h1 = {0.f, 0.f};
        int kb = g * 75, ke = kb + 75;
#pragma unroll 5
        for (int k = kb; k < ke; ++k) {
            f32x2 m2 = *(const f32x2*)&axm2[k * 2];
            h0 += m2 * Ww[k * 300 + t];
            h1 += m2 * Ww[k * 300 + d1];
        }
        *(f32x2*)&axp[g * 608 + t * 2] = h0;
        if (has2) *(f32x2*)&axp[g * 608 + d1 * 2] = h1;
    }
    __syncthreads();

    // ---- h reduce + LN stats ----
    f32x2 hv = {0.f, 0.f};
    int wvi = tid >> 6, lane = tid & 63;
    if (tid < 320) {
        if (tid < 300) {
            hv = *(f32x2*)&axp[tid * 2]        + *(f32x2*)&axp[608 + tid * 2]
               + *(f32x2*)&axp[1216 + tid * 2] + *(f32x2*)&axp[1824 + tid * 2];
            hv += Wb[tid];
        }
        float s1r[2], s2r[2];
#pragma unroll
        for (int r = 0; r < 2; ++r) { s1r[r] = hv[r]; s2r[r] = hv[r] * hv[r]; }
        for (int off = 32; off; off >>= 1) {
#pragma unroll
            for (int r = 0; r < 2; ++r) {
                s1r[r] += __shfl_down(s1r[r], off);
                s2r[r] += __shfl_down(s2r[r], off);
            }
        }
        if (lane == 0) {
#pragma unroll
            for (int r = 0; r < 2; ++r) { red1[wvi * 2 + r] = s1r[r]; red2[wvi * 2 + r] = s2r[r]; }
        }
    }
    __syncthreads();
    if (tid < 2) {
        float s1 = 0.f, s2 = 0.f;
#pragma unroll
        for (int w = 0; w < 5; ++w) { s1 += red1[w * 2 + tid]; s2 += red2[w * 2 + tid]; }
        float mean = s1 * (1.0f / 300.0f);
        float var = (s2 - 300.0f * mean * mean) * (1.0f / 299.0f);
        var = fmaxf(var, 0.0f);
        stats[tid * 2] = mean;
        stats[tid * 2 + 1] = 1.0f / (sqrtf(var) + 1e-6f);
    }
    __syncthreads();

    // ---- apply LN + relu -> node_out + srcL ----
    if (tid < 300) {
        float la = lna[tid], lb = lnb[tid];
        f32x2 nv;
#pragma unroll
        for (int r = 0; r < 2; ++r) {
            float v = la * (hv[r] - stats[r * 2]) * stats[r * 2 + 1] + lb;
            v = fmaxf(v, 0.f);
            nv[r] = v;
            node_out[(size_t)(row0 + r) * 300 + tid] = v;
        }
        *(f32x2*)&srcL[(50 + tid) * 2] = nv;
    }
    __syncthreads();

    // ---- phase 3: R1/R2 partials, 14 chunks of 25 over concat K=350 ----
    if (tid < 700) {
        int p = tid / 50, k = tid % 50;
        f32x2 r1a = {0.f, 0.f}, r2a = {0.f, 0.f};
        int ib = p * 25;
#pragma unroll 5
        for (int idx = ib; idx < ib + 25; ++idx) {
            f32x2 sv = *(const f32x2*)&srcL[idx * 2];
            float w1, w2;
            if (idx < 50) { w1 = Rw[(50 + idx) * 50 + k]; w2 = Rw[(100 + idx) * 50 + k]; }
            else { int d = idx - 50; w1 = Rw[(150 + d) * 50 + k]; w2 = Rw[(450 + d) * 50 + k]; }
            r1a += sv * w1;
            r2a += sv * w2;
        }
        *(f32x2*)&axp[(p * 50 + k) * 2] = r1a;
        *(f32x2*)&axp[2800 + (p * 50 + k) * 2] = r2a;
    }
    __syncthreads();
    if (tid < 100) {
        int r = tid / 50, k = tid % 50;
        float s1 = 0.f, s2 = rb[k];
#pragma unroll
        for (int p = 0; p < 14; ++p) {
            s1 += axp[(p * 50 + k) * 2 + r];
            s2 += axp[2800 + (p * 50 + k) * 2 + r];
        }
        R1[(size_t)(row0 + r) * 50 + k] = s1;
        R2[(size_t)(row0 + r) * 50 + k] = s2;
    }
}

// ---------------- K2: edge_out = wa·Rw[0:50] (MFMA) + R1[j] + R2[i] ------------
__global__ void __launch_bounds__(256) k_edge(
    const float* __restrict__ wa,
    const float* __restrict__ Rw,
    const float* __restrict__ R1, const float* __restrict__ R2,
    float* __restrict__ eout)
{
    __shared__ __align__(16) unsigned char smem[27648];
    unsigned short* waA  = (unsigned short*)smem;            // 128*72 bf16
    unsigned short* rwBT = (unsigned short*)(smem + 18432);  // 64*72 bf16
    float* outF = (float*)smem;                              // alias: 6400 floats
    int tid = threadIdx.x;
    int bi = blockIdx.x;       // b*128 + i
    int b = bi >> 7;

    for (int idx = tid; idx < 2304; idx += 256) ((unsigned int*)rwBT)[idx] = 0u;
    for (int idx = tid; idx < 1408; idx += 256) {            // zero waA pad e in [50,72)
        int j = idx / 11, c = idx % 11;
        *((unsigned int*)(waA + j * 72 + 50) + c) = 0u;
    }
    __syncthreads();

    const float2* wap = (const float2*)(wa + (size_t)bi * 6400);
    for (int idx = tid; idx < 3200; idx += 256) {
        float2 v = wap[idx];
        int f = idx * 2;
        int j = f / 50, e = f % 50;
        unsigned int pack = (unsigned int)f2bf(v.x) | ((unsigned int)f2bf(v.y) << 16);
        *(unsigned int*)(waA + j * 72 + e) = pack;
    }
    for (int idx = tid; idx < 2500; idx += 256) {            // transpose+cvt Rw[0:50][0:50]
        int e = idx / 50, kk = idx % 50;
        rwBT[kk * 72 + e] = f2bf(Rw[idx]);
    }
    __syncthreads();

    int lane = tid & 63, wv = tid >> 6;
    int q = lane >> 4, lr = lane & 15;
    f32x4 acc[2][4] = {};

#pragma unroll
    for (int ks = 0; ks < 2; ++ks) {
        int e0 = ks * 32 + q * 8;
        bf16x8 a0 = *(const bf16x8*)&waA[(wv * 32 + lr) * 72 + e0];
        bf16x8 a1 = *(const bf16x8*)&waA[(wv * 32 + 16 + lr) * 72 + e0];
#pragma unroll
        for (int nt = 0; nt < 4; ++nt) {
            bf16x8 bb = *(const bf16x8*)&rwBT[(nt * 16 + lr) * 72 + e0];
            acc[0][nt] = __builtin_amdgcn_mfma_f32_16x16x32_bf16(a0, bb, acc[0][nt], 0, 0, 0);
            acc[1][nt] = __builtin_amdgcn_mfma_f32_16x16x32_bf16(a1, bb, acc[1][nt], 0, 0, 0);
        }
    }
    __syncthreads();   // staging LDS dead; alias as outF

    const float* r2p = R2 + (size_t)bi * 50;
#pragma unroll
    for (int nt = 0; nt < 4; ++nt) {
        int kk = nt * 16 + lr;
        if (kk < 50) {
            float r2v = r2p[kk];
#pragma unroll
            for (int mi = 0; mi < 2; ++mi) {
                int jbase = wv * 32 + mi * 16 + q * 4;
#pragma unroll
                for (int r = 0; r < 4; ++r)
                    outF[(jbase + r) * 50 + kk] = acc[mi][nt][r] + r2v;
            }
        }
    }
    __syncthreads();

    const float4* R1b = (const float4*)(R1 + (size_t)b * 6400);
    const float4* L4  = (const float4*)outF;
    float4* op4 = (float4*)(eout + (size_t)bi * 6400);
    for (int f4 = tid; f4 < 1600; f4 += 256) {
        float4 v = L4[f4];
        float4 r = R1b[f4];
        v.x += r.x; v.y += r.y; v.z += r.z; v.w += r.w;
        op4[f4] = v;
    }
}

extern "C" void kernel_launch(void* const* d_in, const int* in_sizes, int n_in,
                              void* d_out, int out_size, void* d_ws, size_t ws_size,
                              hipStream_t stream)
{
    const float* wps = (const float*)d_in[0];
    const float* wa  = (const float*)d_in[1];
    const float* x   = (const float*)d_in[2];
    // d_in[3] self_loop: identity on every channel, folded into fused msum (+1 on diag)
    const float* Ww  = (const float*)d_in[4];
    const float* Wb  = (const float*)d_in[5];
    const float* lna = (const float*)d_in[6];
    const float* lnb = (const float*)d_in[7];
    const float* Rw  = (const float*)d_in[8];
    const float* rb  = (const float*)d_in[9];

    float* R1 = (float*)d_ws;                    // 51200 floats
    float* R2 = ((float*)d_ws) + 51200;          // 51200 floats

    float* node_out = (float*)d_out;             // 307200 floats
    float* edge_out = node_out + 307200;         // 6553600 floats

    k_node<<<512, 1024, 0, stream>>>(wps, wa, x, Ww, Wb, lna, lnb, Rw, rb,
                                     node_out, R1, R2);
    k_edge<<<1024, 256, 0, stream>>>(wa, Rw, R1, R2, edge_out);
}